// Round 8
// baseline (258.089 us; speedup 1.0000x reference)
//
#include <hip/hip_runtime.h>
#include <hip/hip_bf16.h>
#include <cstdint>

// Problem: out = x @ (W + scale*B@A)^T + b
//   x[4,2048,2048] -> X[M=8192, K=2048],  W[N=2048, K=2048], b[N],
//   A[R=16, K], B[N, R=16], scale scalar.  ALL I/O IS FLOAT32.
// R7:  16x16 MFMA, m201 cadence -> 75.4us GEMM, 207.5 total.
// R10: 32x32x16 MFMA -> 78.3us: 4-way LDS conflict (6.29M).
// R11: involution f(r)=(r&7)^((r>>3)&3) both sides -> conflicts 0,
//      GEMM 72-73us, MfmaUtil 40%, total 209.5.
// R12: fold x fp32->bf16 cvt into GEMM A-staging, 2-phase issue->write
//      lead, two named in-flight sets. COMPILE FAIL: S##2.y pastes with
//      pp-number "2.y" -> invalid token.
// R13: same design, sets as float4 arrays qA[4]/qB[4] (no token pasting;
//      all indices literal -> stays in registers). Aux = Weff only.

typedef __bf16 bf16x8 __attribute__((ext_vector_type(8)));
typedef float floatx16 __attribute__((ext_vector_type(16)));
typedef unsigned short ushort8 __attribute__((ext_vector_type(8)));

#define BM 256
#define BN 256
#define BK 64
#define NT 32   // K / BK

__device__ __forceinline__ void gload_lds16(const void* g, void* l) {
    // 16B-per-lane async global->LDS. LDS dest must be wave-uniform base + lane*16.
    __builtin_amdgcn_global_load_lds((__attribute__((address_space(1))) void*)g,
                                     (__attribute__((address_space(3))) void*)l,
                                     16, 0, 0);
}

// fp32 -> bf16 bits, round-to-nearest-even (finite inputs only).
__device__ __forceinline__ unsigned short f2bf_bits(float f) {
    unsigned int u = __float_as_uint(f);
    u += 0x7FFFu + ((u >> 16) & 1u);
    return (unsigned short)(u >> 16);
}

// ---------------------------------------------------------------------------
// Aux kernel: Weff = bf16(W + scale*B@A) only. 2048 blocks (~24 MB traffic).
// ---------------------------------------------------------------------------
__global__ __launch_bounds__(256)
void aux_kernel(const float* __restrict__ W, const float* __restrict__ A,
                const float* __restrict__ Bm, const float* __restrict__ scale_p,
                unsigned short* __restrict__ Weff)
{
    const int K = 2048, R = 16;
    int t  = blockIdx.x * 256 + threadIdx.x;
    int n  = t >> 8;
    int k8 = (t & 255) << 3;

    float s = *scale_p;
    float br[16];
#pragma unroll
    for (int r = 0; r < R; ++r)
        br[r] = s * Bm[n * R + r];

    float acc[8] = {0,0,0,0,0,0,0,0};
#pragma unroll
    for (int r = 0; r < R; ++r) {
        const float* ap = A + r * K + k8;
#pragma unroll
        for (int j = 0; j < 8; ++j)
            acc[j] += br[r] * ap[j];
    }

    const float* wp = W + (size_t)n * K + k8;
    ushort8 o;
#pragma unroll
    for (int j = 0; j < 8; ++j)
        o[j] = f2bf_bits(wp[j] + acc[j]);
    *reinterpret_cast<ushort8*>(Weff + (size_t)n * K + k8) = o;
}

// ---------------------------------------------------------------------------
// GEMM: out[M,N] (fp32) = bf16(x)[M,K] @ Weffbf[N,K]^T + bias (fp32)
//
// LDS regions (16 KB each, 128 KiB total):
//   Sa[buf][mh]: A M-half [wrH(2)][64 r][64 c bf16], rows bm+wrH*128+mh*64+r.
//                Reg-staged fp32->bf16 ds_write_b128; swizzle on the WRITE
//                (global fp32 source linear).
//   Sb[buf][nh]: B N-half [wcH(4)][32 r][64 c]; global_load_lds, linear
//                dest, pre-swizzled source.
// Swizzle involution (both sides): 16B slot s -> s ^ (r&7) ^ ((r>>3)&3).
// Measured 0 bank conflicts (R11).
//
// MFMA 32x32x16: lane row l31=lane&31, k-window kg=(lane>>5)*8; 8 MFMA per
// (mh,nh) quadrant. bqa lives P1->P4, bqb P2->P3; P4/P8 have 0 ds_reads.
//
// Per-iteration slots (steady state; issue order STAGE_B before AISSUE):
//   P1: Bgl Sb[1][0]<-t1; qB<-(mh0,t2)    P2: wr Sa[1][1](qA)
//   P3: wr Sa[0][0](qB)                   P4: Bgl Sb[0][1]<-t2; qA<-(mh1,t2)
//   P5: Bgl Sb[0][0]<-t2; qB<-(mh0,t3)    P6: wr Sa[0][1](qA)
//   P7: wr Sa[1][0](qB)                   P8: Bgl Sb[1][1]<-t3; qA<-(mh1,t3)
// Issue->write lead = 2 phases (~2600 cy >> 900 cy HBM). Compiler vmcnt
// waits before each AWRITE retire (FIFO) all older B-gloads:
//   Bgl(P1)@P3, Bgl(P4)@P6, Bgl(P5)@P7, Bgl(P8)@P2' — each >=2 phases
// before that region's first ds_read. Region liveness identical to R11.
// ---------------------------------------------------------------------------
#define BAR()       __builtin_amdgcn_s_barrier()
#define WAIT_LGKM() asm volatile("s_waitcnt lgkmcnt(0)" ::: "memory")
#define WAIT_VM0()  asm volatile("s_waitcnt vmcnt(0)" ::: "memory")

#define STAGE_B(buf, nh, kt) do {                                             \
    gload_lds16(gB0 + (size_t)(nh) * 32 * 2048 + (kt) * 64, &Sb[buf][nh][c0 * 8]); \
    gload_lds16(gB1 + (size_t)(nh) * 32 * 2048 + (kt) * 64, &Sb[buf][nh][c1 * 8]); \
} while (0)

// Issue 16 fp32 x-loads (4x float4) into set S for A-region (mh, kt).
#define AISSUE_S(S, mh, kt) do {                                              \
    const float* xp = xA + (size_t)(mh) * 64 * 2048 + (kt) * 64;              \
    S[0] = *reinterpret_cast<const float4*>(xp);                              \
    S[1] = *reinterpret_cast<const float4*>(xp + 4);                          \
    S[2] = *reinterpret_cast<const float4*>(xp + 128 * 2048);                 \
    S[3] = *reinterpret_cast<const float4*>(xp + 128 * 2048 + 4);             \
} while (0)

// Convert set S + swizzled ds_write into Sa[buf][mh] (both wrH blocks).
#define AWRITE_S(S, buf, mh) do {                                             \
    ushort8 o0, o1;                                                           \
    o0[0]=f2bf_bits(S[0].x); o0[1]=f2bf_bits(S[0].y); o0[2]=f2bf_bits(S[0].z);\
    o0[3]=f2bf_bits(S[0].w); o0[4]=f2bf_bits(S[1].x); o0[5]=f2bf_bits(S[1].y);\
    o0[6]=f2bf_bits(S[1].z); o0[7]=f2bf_bits(S[1].w);                         \
    o1[0]=f2bf_bits(S[2].x); o1[1]=f2bf_bits(S[2].y); o1[2]=f2bf_bits(S[2].z);\
    o1[3]=f2bf_bits(S[2].w); o1[4]=f2bf_bits(S[3].x); o1[5]=f2bf_bits(S[3].y);\
    o1[6]=f2bf_bits(S[3].z); o1[7]=f2bf_bits(S[3].w);                         \
    *reinterpret_cast<ushort8*>(&Sa[buf][mh][dstA])        = o0;              \
    *reinterpret_cast<ushort8*>(&Sa[buf][mh][dstA + 4096]) = o1;              \
} while (0)

// af[mb][ks] <- A quadrant (mh). 8 x ds_read_b128.
#define READ_A(buf, mh) do {                                                  \
    const unsigned short* ra = &Sa[buf][mh][(wr * 64 + l31) * 64];            \
    _Pragma("unroll")                                                         \
    for (int ks = 0; ks < 4; ++ks) {                                          \
        af[0][ks] = *reinterpret_cast<const bf16x8*>(ra + swzk[ks]);          \
        af[1][ks] = *reinterpret_cast<const bf16x8*>(ra + 2048 + swzk[ks]);   \
    }                                                                         \
} while (0)

// BQ[ks] <- B n-block (nh). 4 x ds_read_b128.
#define READ_B(buf, nh, BQ) do {                                              \
    const unsigned short* rb = &Sb[buf][nh][(wc * 32 + l31) * 64];            \
    _Pragma("unroll")                                                         \
    for (int ks = 0; ks < 4; ++ks)                                            \
        BQ[ks] = *reinterpret_cast<const bf16x8*>(rb + swzk[ks]);             \
} while (0)

// 8 x mfma_f32_32x32x16_bf16.
#define MFMAQ(mh, nh, BQ) do {                                                \
    __builtin_amdgcn_s_setprio(1);                                            \
    _Pragma("unroll")                                                         \
    for (int ks = 0; ks < 4; ++ks) {                                          \
        acc[(mh)*2+0][nh] = __builtin_amdgcn_mfma_f32_32x32x16_bf16(          \
            af[0][ks], BQ[ks], acc[(mh)*2+0][nh], 0, 0, 0);                   \
        acc[(mh)*2+1][nh] = __builtin_amdgcn_mfma_f32_32x32x16_bf16(          \
            af[1][ks], BQ[ks], acc[(mh)*2+1][nh], 0, 0, 0);                   \
    }                                                                         \
    __builtin_amdgcn_s_setprio(0);                                            \
} while (0)

__global__ __launch_bounds__(512, 2)
void gemm_bias_kernel(const float* __restrict__ x,
                      const unsigned short* __restrict__ Wt,
                      const float* __restrict__ bias,
                      float* __restrict__ out)
{
    const int N = 2048, K = 2048;

    __shared__ alignas(16) unsigned short Sa[2][2][8192];   // 64 KB
    __shared__ alignas(16) unsigned short Sb[2][2][8192];   // 64 KB

    const int tid  = threadIdx.x;
    const int wave = tid >> 6;
    const int lane = tid & 63;
    const int l31  = lane & 31;
    const int kg   = lane >> 5;   // k-window selector for 32x32 fragments
    const int l7   = lane & 7;
    const int wr   = wave >> 2;   // 0..1  (M split)
    const int wc   = wave & 3;    // 0..3  (N split)

    // XCD-rectangle swizzle (bijective, 256 % 8 == 0).
    const int id  = blockIdx.x;            // 0..255
    const int xcd = id & 7;
    const int sg  = id >> 3;               // 0..31
    const int bm  = (xcd * 4 + (sg & 3)) * BM;
    const int bn  = (sg >> 2) * BN;

    // --- A staging (reg-staged fp32 -> cvt -> swizzled ds_write).
    // Thread granule: row ar=(tid>>3)&63, slot as=tid&7; S[2]/S[3] cover
    // wrH1 (+128 rows). Global fp32 source LINEAR; swizzle on the write.
    const int ar = (tid >> 3) & 63;
    const int as = tid & 7;
    const float* xA = x + (size_t)(bm + ar) * K + as * 8;
    const int dstA = ar * 64 + ((as ^ (ar & 7) ^ ((ar >> 3) & 3)) << 3);
    float4 qA[4];     // in-flight set A (literal indices only)
    float4 qB[4];     // in-flight set B

    // --- B staging (global_load_lds, pre-swizzled source, f(r) involution).
    const int c0 = tid, c1 = tid + 512;
    const int as1 = c1 & 7;
    const int br0 = (c0 >> 3) & 31, br1 = (c1 >> 3) & 31;
    const unsigned short* gB0 = Wt + (size_t)(bn + (c0 >> 8) * 64 + br0) * K
                                   + ((as  ^ (br0 & 7) ^ ((br0 >> 3) & 3)) << 3);
    const unsigned short* gB1 = Wt + (size_t)(bn + (c1 >> 8) * 64 + br1) * K
                                   + ((as1 ^ (br1 & 7) ^ ((br1 >> 3) & 3)) << 3);

    // ds_read swizzle: logical 16B granule g = ks*2 + kg, phys = g ^ f(row);
    // f(row) = l7 ^ (l31>>3) for every fragment row (offsets ==0 mod 32).
    const int fr   = l7 ^ (l31 >> 3);
    const int swzk[4] = { ((0 + kg) ^ fr) << 3, ((2 + kg) ^ fr) << 3,
                          ((4 + kg) ^ fr) << 3, ((6 + kg) ^ fr) << 3 };

    floatx16 acc[4][2] = {};   // [m-block 0..3][n-block 0..1]
    bf16x8 af[2][4];           // [mb within quadrant][ks]
    bf16x8 bqa[4], bqb[4];     // nh0 (lives P1->P4), nh1 (P2->P3)

    // Prologue: B t0 (both) + B t1-n1 via gload FIRST (so later q-waits
    // retire them); A t0 (both) + A t1-mh0 cvt'd directly; A t1-mh1 left
    // in flight in qA for P2. Full drain before loop.
    STAGE_B(0, 1, 0);
    STAGE_B(0, 0, 0);
    STAGE_B(1, 1, 1);
    AISSUE_S(qB, 0, 0); AWRITE_S(qB, 0, 0);   // Sa[0][0] <- mh0, t0
    AISSUE_S(qB, 1, 0); AWRITE_S(qB, 0, 1);   // Sa[0][1] <- mh1, t0
    AISSUE_S(qB, 0, 1); AWRITE_S(qB, 1, 0);   // Sa[1][0] <- mh0, t1
    AISSUE_S(qA, 1, 1);                       // in flight: Sa[1][1] <- mh1, t1
    WAIT_VM0(); WAIT_LGKM(); BAR();

#pragma unroll 1
    for (int tt = 0; tt < NT; tt += 2) {
        const int t1 = tt + 1;
        const int t2 = (tt + 2 < NT) ? tt + 2 : NT - 1;   // clamped tail
        const int t3 = (tt + 3 < NT) ? tt + 3 : NT - 1;   // (dead regions)

        // ---- tile t (buf0) ----
        // P1 (m0,n0)
        READ_A(0, 0); READ_B(0, 0, bqa);
        STAGE_B(1, 0, t1);
        AISSUE_S(qB, 0, t2);
        BAR(); WAIT_LGKM(); MFMAQ(0, 0, bqa); BAR();
        // P2 (m0,n1)
        AWRITE_S(qA, 1, 1);
        READ_B(0, 1, bqb);
        BAR(); WAIT_LGKM(); MFMAQ(0, 1, bqb); BAR();
        // P3 (m1,n1)
        AWRITE_S(qB, 0, 0);
        READ_A(0, 1);
        BAR(); WAIT_LGKM(); MFMAQ(1, 1, bqb); BAR();
        // P4 (m1,n0) — zero ds_reads (bqa still live)
        STAGE_B(0, 1, t2);
        AISSUE_S(qA, 1, t2);
        BAR(); WAIT_LGKM(); MFMAQ(1, 0, bqa); BAR();

        // ---- tile t+1 (buf1) ----
        // P5 (m0,n0)
        READ_A(1, 0); READ_B(1, 0, bqa);
        STAGE_B(0, 0, t2);
        AISSUE_S(qB, 0, t3);
        BAR(); WAIT_LGKM(); MFMAQ(0, 0, bqa); BAR();
        // P6 (m0,n1)
        AWRITE_S(qA, 0, 1);
        READ_B(1, 1, bqb);
        BAR(); WAIT_LGKM(); MFMAQ(0, 1, bqb); BAR();
        // P7 (m1,n1)
        AWRITE_S(qB, 1, 0);
        READ_A(1, 1);
        BAR(); WAIT_LGKM(); MFMAQ(1, 1, bqb); BAR();
        // P8 (m1,n0) — zero ds_reads
        STAGE_B(1, 1, t3);
        AISSUE_S(qA, 1, t3);   // Sa[1][1] <- mh1, t1 of next iter
        BAR(); WAIT_LGKM(); MFMAQ(1, 0, bqa); BAR();
    }
    WAIT_VM0();   // drain tail loads before epilogue stores

    // Epilogue. 32x32 C/D layout (m74/m101): col = lane&31,
    // row = (reg&3) + 8*(reg>>2) + 4*(lane>>5), reg in [0,16).
    const float bsv0 = bias[bn + wc * 64 + l31];
    const float bsv1 = bias[bn + wc * 64 + 32 + l31];
    const size_t cb  = (size_t)bn + wc * 64 + l31;
#pragma unroll
    for (int mb = 0; mb < 4; ++mb) {
#pragma unroll
        for (int r = 0; r < 16; ++r) {
            size_t rowoff = (size_t)(bm + wr * 128 + mb * 32
                                     + (r & 3) + ((r >> 2) << 3) + (kg << 2)) * N;
            out[rowoff + cb]      = acc[mb][0][r] + bsv0;
            out[rowoff + cb + 32] = acc[mb][1][r] + bsv1;
        }
    }
}

extern "C" void kernel_launch(void* const* d_in, const int* in_sizes, int n_in,
                              void* d_out, int out_size, void* d_ws, size_t ws_size,
                              hipStream_t stream)
{
    const float* x  = (const float*)d_in[0];
    const float* W  = (const float*)d_in[1];
    const float* b  = (const float*)d_in[2];
    const float* A  = (const float*)d_in[3];
    const float* Bm = (const float*)d_in[4];
    const float* sc = (const float*)d_in[5];
    float* out = (float*)d_out;

    const size_t M = 8192, N = 2048, K = 2048;

    unsigned short* Weff = (unsigned short*)d_ws;   // 8 MB

    // 1) Weff = bf16(W + scale * B@A)
    aux_kernel<<<dim3(N * K / 8 / 256), dim3(256), 0, stream>>>(
        W, A, Bm, sc, Weff);

    // 2) out = bf16(x) @ Weff^T + b  (x cvt fused into A-staging)
    gemm_bias_kernel<<<dim3((M / BM) * (N / BN)), dim3(512), 0, stream>>>(
        x, Weff, b, out);
}

// Round 9
// 256.440 us; speedup vs baseline: 1.0064x; 1.0064x over previous
//
#include <hip/hip_runtime.h>
#include <hip/hip_bf16.h>
#include <cstdint>

// Problem: out = x @ (W + scale*B@A)^T + b
//   x[4,2048,2048] -> X[M=8192, K=2048],  W[N=2048, K=2048], b[N],
//   A[R=16, K], B[N, R=16], scale scalar.  ALL I/O IS FLOAT32.
// R11: 32x32 MFMA + f(r)=(r&7)^((r>>3)&3) swizzle -> GEMM 72.6us, total 209.5.
// R9/R13: x-cvt fused into GEMM A-staging -> 126/144us GEMM. Post-mortem:
//      BOTH carried __launch_bounds__(512,2) => 128-VGPR cap while live set
//      needs ~240 (acc 128 + frags 64 + q-sets 32 + addr) => scratch spill.
//      Evidence: WRITE_SIZE +14MB (not output!), FETCH +21MB, and R13
//      (2 q-sets) slower than R9 (1 q-set) — spill scales with live regs.
//      R11 (no ",2") was fine. The ",2" is also pointless: 128KB LDS means
//      1 block/CU regardless.
// R14: R13 verbatim EXCEPT __launch_bounds__(512) — isolate the spill fix.

typedef __bf16 bf16x8 __attribute__((ext_vector_type(8)));
typedef float floatx16 __attribute__((ext_vector_type(16)));
typedef unsigned short ushort8 __attribute__((ext_vector_type(8)));

#define BM 256
#define BN 256
#define BK 64
#define NT 32   // K / BK

__device__ __forceinline__ void gload_lds16(const void* g, void* l) {
    // 16B-per-lane async global->LDS. LDS dest must be wave-uniform base + lane*16.
    __builtin_amdgcn_global_load_lds((__attribute__((address_space(1))) void*)g,
                                     (__attribute__((address_space(3))) void*)l,
                                     16, 0, 0);
}

// fp32 -> bf16 bits, round-to-nearest-even (finite inputs only).
__device__ __forceinline__ unsigned short f2bf_bits(float f) {
    unsigned int u = __float_as_uint(f);
    u += 0x7FFFu + ((u >> 16) & 1u);
    return (unsigned short)(u >> 16);
}

// ---------------------------------------------------------------------------
// Aux kernel: Weff = bf16(W + scale*B@A) only. 2048 blocks (~24 MB traffic).
// ---------------------------------------------------------------------------
__global__ __launch_bounds__(256)
void aux_kernel(const float* __restrict__ W, const float* __restrict__ A,
                const float* __restrict__ Bm, const float* __restrict__ scale_p,
                unsigned short* __restrict__ Weff)
{
    const int K = 2048, R = 16;
    int t  = blockIdx.x * 256 + threadIdx.x;
    int n  = t >> 8;
    int k8 = (t & 255) << 3;

    float s = *scale_p;
    float br[16];
#pragma unroll
    for (int r = 0; r < R; ++r)
        br[r] = s * Bm[n * R + r];

    float acc[8] = {0,0,0,0,0,0,0,0};
#pragma unroll
    for (int r = 0; r < R; ++r) {
        const float* ap = A + r * K + k8;
#pragma unroll
        for (int j = 0; j < 8; ++j)
            acc[j] += br[r] * ap[j];
    }

    const float* wp = W + (size_t)n * K + k8;
    ushort8 o;
#pragma unroll
    for (int j = 0; j < 8; ++j)
        o[j] = f2bf_bits(wp[j] + acc[j]);
    *reinterpret_cast<ushort8*>(Weff + (size_t)n * K + k8) = o;
}

// ---------------------------------------------------------------------------
// GEMM: out[M,N] (fp32) = bf16(x)[M,K] @ Weffbf[N,K]^T + bias (fp32)
//
// LDS regions (16 KB each, 128 KiB total):
//   Sa[buf][mh]: A M-half [wrH(2)][64 r][64 c bf16], rows bm+wrH*128+mh*64+r.
//                Reg-staged fp32->bf16 ds_write_b128; swizzle on the WRITE
//                (global fp32 source linear).
//   Sb[buf][nh]: B N-half [wcH(4)][32 r][64 c]; global_load_lds, linear
//                dest, pre-swizzled source.
// Swizzle involution (both sides): 16B slot s -> s ^ (r&7) ^ ((r>>3)&3).
// Measured 0 bank conflicts (R11).
//
// MFMA 32x32x16: lane row l31=lane&31, k-window kg=(lane>>5)*8; 8 MFMA per
// (mh,nh) quadrant. bqa lives P1->P4, bqb P2->P3; P4/P8 have 0 ds_reads.
//
// Per-iteration slots (steady state; issue order STAGE_B before AISSUE):
//   P1: Bgl Sb[1][0]<-t1; qB<-(mh0,t2)    P2: wr Sa[1][1](qA)
//   P3: wr Sa[0][0](qB)                   P4: Bgl Sb[0][1]<-t2; qA<-(mh1,t2)
//   P5: Bgl Sb[0][0]<-t2; qB<-(mh0,t3)    P6: wr Sa[0][1](qA)
//   P7: wr Sa[1][0](qB)                   P8: Bgl Sb[1][1]<-t3; qA<-(mh1,t3)
// Issue->write lead = 2 phases (~2600 cy >> 900 cy HBM). Compiler vmcnt
// waits before each AWRITE retire (FIFO) all older B-gloads:
//   Bgl(P1)@P3, Bgl(P4)@P6, Bgl(P5)@P7, Bgl(P8)@P2' — each >=2 phases
// before that region's first ds_read. Region liveness identical to R11.
// ---------------------------------------------------------------------------
#define BAR()       __builtin_amdgcn_s_barrier()
#define WAIT_LGKM() asm volatile("s_waitcnt lgkmcnt(0)" ::: "memory")
#define WAIT_VM0()  asm volatile("s_waitcnt vmcnt(0)" ::: "memory")

#define STAGE_B(buf, nh, kt) do {                                             \
    gload_lds16(gB0 + (size_t)(nh) * 32 * 2048 + (kt) * 64, &Sb[buf][nh][c0 * 8]); \
    gload_lds16(gB1 + (size_t)(nh) * 32 * 2048 + (kt) * 64, &Sb[buf][nh][c1 * 8]); \
} while (0)

// Issue 16 fp32 x-loads (4x float4) into set S for A-region (mh, kt).
#define AISSUE_S(S, mh, kt) do {                                              \
    const float* xp = xA + (size_t)(mh) * 64 * 2048 + (kt) * 64;              \
    S[0] = *reinterpret_cast<const float4*>(xp);                              \
    S[1] = *reinterpret_cast<const float4*>(xp + 4);                          \
    S[2] = *reinterpret_cast<const float4*>(xp + 128 * 2048);                 \
    S[3] = *reinterpret_cast<const float4*>(xp + 128 * 2048 + 4);             \
} while (0)

// Convert set S + swizzled ds_write into Sa[buf][mh] (both wrH blocks).
#define AWRITE_S(S, buf, mh) do {                                             \
    ushort8 o0, o1;                                                           \
    o0[0]=f2bf_bits(S[0].x); o0[1]=f2bf_bits(S[0].y); o0[2]=f2bf_bits(S[0].z);\
    o0[3]=f2bf_bits(S[0].w); o0[4]=f2bf_bits(S[1].x); o0[5]=f2bf_bits(S[1].y);\
    o0[6]=f2bf_bits(S[1].z); o0[7]=f2bf_bits(S[1].w);                         \
    o1[0]=f2bf_bits(S[2].x); o1[1]=f2bf_bits(S[2].y); o1[2]=f2bf_bits(S[2].z);\
    o1[3]=f2bf_bits(S[2].w); o1[4]=f2bf_bits(S[3].x); o1[5]=f2bf_bits(S[3].y);\
    o1[6]=f2bf_bits(S[3].z); o1[7]=f2bf_bits(S[3].w);                         \
    *reinterpret_cast<ushort8*>(&Sa[buf][mh][dstA])        = o0;              \
    *reinterpret_cast<ushort8*>(&Sa[buf][mh][dstA + 4096]) = o1;              \
} while (0)

// af[mb][ks] <- A quadrant (mh). 8 x ds_read_b128.
#define READ_A(buf, mh) do {                                                  \
    const unsigned short* ra = &Sa[buf][mh][(wr * 64 + l31) * 64];            \
    _Pragma("unroll")                                                         \
    for (int ks = 0; ks < 4; ++ks) {                                          \
        af[0][ks] = *reinterpret_cast<const bf16x8*>(ra + swzk[ks]);          \
        af[1][ks] = *reinterpret_cast<const bf16x8*>(ra + 2048 + swzk[ks]);   \
    }                                                                         \
} while (0)

// BQ[ks] <- B n-block (nh). 4 x ds_read_b128.
#define READ_B(buf, nh, BQ) do {                                              \
    const unsigned short* rb = &Sb[buf][nh][(wc * 32 + l31) * 64];            \
    _Pragma("unroll")                                                         \
    for (int ks = 0; ks < 4; ++ks)                                            \
        BQ[ks] = *reinterpret_cast<const bf16x8*>(rb + swzk[ks]);             \
} while (0)

// 8 x mfma_f32_32x32x16_bf16.
#define MFMAQ(mh, nh, BQ) do {                                                \
    __builtin_amdgcn_s_setprio(1);                                            \
    _Pragma("unroll")                                                         \
    for (int ks = 0; ks < 4; ++ks) {                                          \
        acc[(mh)*2+0][nh] = __builtin_amdgcn_mfma_f32_32x32x16_bf16(          \
            af[0][ks], BQ[ks], acc[(mh)*2+0][nh], 0, 0, 0);                   \
        acc[(mh)*2+1][nh] = __builtin_amdgcn_mfma_f32_32x32x16_bf16(          \
            af[1][ks], BQ[ks], acc[(mh)*2+1][nh], 0, 0, 0);                   \
    }                                                                         \
    __builtin_amdgcn_s_setprio(0);                                            \
} while (0)

__global__ __launch_bounds__(512)
void gemm_bias_kernel(const float* __restrict__ x,
                      const unsigned short* __restrict__ Wt,
                      const float* __restrict__ bias,
                      float* __restrict__ out)
{
    const int N = 2048, K = 2048;

    __shared__ alignas(16) unsigned short Sa[2][2][8192];   // 64 KB
    __shared__ alignas(16) unsigned short Sb[2][2][8192];   // 64 KB

    const int tid  = threadIdx.x;
    const int wave = tid >> 6;
    const int lane = tid & 63;
    const int l31  = lane & 31;
    const int kg   = lane >> 5;   // k-window selector for 32x32 fragments
    const int l7   = lane & 7;
    const int wr   = wave >> 2;   // 0..1  (M split)
    const int wc   = wave & 3;    // 0..3  (N split)

    // XCD-rectangle swizzle (bijective, 256 % 8 == 0).
    const int id  = blockIdx.x;            // 0..255
    const int xcd = id & 7;
    const int sg  = id >> 3;               // 0..31
    const int bm  = (xcd * 4 + (sg & 3)) * BM;
    const int bn  = (sg >> 2) * BN;

    // --- A staging (reg-staged fp32 -> cvt -> swizzled ds_write).
    // Thread granule: row ar=(tid>>3)&63, slot as=tid&7; S[2]/S[3] cover
    // wrH1 (+128 rows). Global fp32 source LINEAR; swizzle on the write.
    const int ar = (tid >> 3) & 63;
    const int as = tid & 7;
    const float* xA = x + (size_t)(bm + ar) * K + as * 8;
    const int dstA = ar * 64 + ((as ^ (ar & 7) ^ ((ar >> 3) & 3)) << 3);
    float4 qA[4];     // in-flight set A (literal indices only)
    float4 qB[4];     // in-flight set B

    // --- B staging (global_load_lds, pre-swizzled source, f(r) involution).
    const int c0 = tid, c1 = tid + 512;
    const int as1 = c1 & 7;
    const int br0 = (c0 >> 3) & 31, br1 = (c1 >> 3) & 31;
    const unsigned short* gB0 = Wt + (size_t)(bn + (c0 >> 8) * 64 + br0) * K
                                   + ((as  ^ (br0 & 7) ^ ((br0 >> 3) & 3)) << 3);
    const unsigned short* gB1 = Wt + (size_t)(bn + (c1 >> 8) * 64 + br1) * K
                                   + ((as1 ^ (br1 & 7) ^ ((br1 >> 3) & 3)) << 3);

    // ds_read swizzle: logical 16B granule g = ks*2 + kg, phys = g ^ f(row);
    // f(row) = l7 ^ (l31>>3) for every fragment row (offsets ==0 mod 32).
    const int fr   = l7 ^ (l31 >> 3);
    const int swzk[4] = { ((0 + kg) ^ fr) << 3, ((2 + kg) ^ fr) << 3,
                          ((4 + kg) ^ fr) << 3, ((6 + kg) ^ fr) << 3 };

    floatx16 acc[4][2] = {};   // [m-block 0..3][n-block 0..1]
    bf16x8 af[2][4];           // [mb within quadrant][ks]
    bf16x8 bqa[4], bqb[4];     // nh0 (lives P1->P4), nh1 (P2->P3)

    // Prologue: B t0 (both) + B t1-n1 via gload FIRST (so later q-waits
    // retire them); A t0 (both) + A t1-mh0 cvt'd directly; A t1-mh1 left
    // in flight in qA for P2. Full drain before loop.
    STAGE_B(0, 1, 0);
    STAGE_B(0, 0, 0);
    STAGE_B(1, 1, 1);
    AISSUE_S(qB, 0, 0); AWRITE_S(qB, 0, 0);   // Sa[0][0] <- mh0, t0
    AISSUE_S(qB, 1, 0); AWRITE_S(qB, 0, 1);   // Sa[0][1] <- mh1, t0
    AISSUE_S(qB, 0, 1); AWRITE_S(qB, 1, 0);   // Sa[1][0] <- mh0, t1
    AISSUE_S(qA, 1, 1);                       // in flight: Sa[1][1] <- mh1, t1
    WAIT_VM0(); WAIT_LGKM(); BAR();

#pragma unroll 1
    for (int tt = 0; tt < NT; tt += 2) {
        const int t1 = tt + 1;
        const int t2 = (tt + 2 < NT) ? tt + 2 : NT - 1;   // clamped tail
        const int t3 = (tt + 3 < NT) ? tt + 3 : NT - 1;   // (dead regions)

        // ---- tile t (buf0) ----
        // P1 (m0,n0)
        READ_A(0, 0); READ_B(0, 0, bqa);
        STAGE_B(1, 0, t1);
        AISSUE_S(qB, 0, t2);
        BAR(); WAIT_LGKM(); MFMAQ(0, 0, bqa); BAR();
        // P2 (m0,n1)
        AWRITE_S(qA, 1, 1);
        READ_B(0, 1, bqb);
        BAR(); WAIT_LGKM(); MFMAQ(0, 1, bqb); BAR();
        // P3 (m1,n1)
        AWRITE_S(qB, 0, 0);
        READ_A(0, 1);
        BAR(); WAIT_LGKM(); MFMAQ(1, 1, bqb); BAR();
        // P4 (m1,n0) — zero ds_reads (bqa still live)
        STAGE_B(0, 1, t2);
        AISSUE_S(qA, 1, t2);
        BAR(); WAIT_LGKM(); MFMAQ(1, 0, bqa); BAR();

        // ---- tile t+1 (buf1) ----
        // P5 (m0,n0)
        READ_A(1, 0); READ_B(1, 0, bqa);
        STAGE_B(0, 0, t2);
        AISSUE_S(qB, 0, t3);
        BAR(); WAIT_LGKM(); MFMAQ(0, 0, bqa); BAR();
        // P6 (m0,n1)
        AWRITE_S(qA, 0, 1);
        READ_B(1, 1, bqb);
        BAR(); WAIT_LGKM(); MFMAQ(0, 1, bqb); BAR();
        // P7 (m1,n1)
        AWRITE_S(qB, 1, 0);
        READ_A(1, 1);
        BAR(); WAIT_LGKM(); MFMAQ(1, 1, bqb); BAR();
        // P8 (m1,n0) — zero ds_reads
        STAGE_B(1, 1, t3);
        AISSUE_S(qA, 1, t3);   // Sa[1][1] <- mh1, t1 of next iter
        BAR(); WAIT_LGKM(); MFMAQ(1, 0, bqa); BAR();
    }
    WAIT_VM0();   // drain tail loads before epilogue stores

    // Epilogue. 32x32 C/D layout (m74/m101): col = lane&31,
    // row = (reg&3) + 8*(reg>>2) + 4*(lane>>5), reg in [0,16).
    const float bsv0 = bias[bn + wc * 64 + l31];
    const float bsv1 = bias[bn + wc * 64 + 32 + l31];
    const size_t cb  = (size_t)bn + wc * 64 + l31;
#pragma unroll
    for (int mb = 0; mb < 4; ++mb) {
#pragma unroll
        for (int r = 0; r < 16; ++r) {
            size_t rowoff = (size_t)(bm + wr * 128 + mb * 32
                                     + (r & 3) + ((r >> 2) << 3) + (kg << 2)) * N;
            out[rowoff + cb]      = acc[mb][0][r] + bsv0;
            out[rowoff + cb + 32] = acc[mb][1][r] + bsv1;
        }
    }
}

extern "C" void kernel_launch(void* const* d_in, const int* in_sizes, int n_in,
                              void* d_out, int out_size, void* d_ws, size_t ws_size,
                              hipStream_t stream)
{
    const float* x  = (const float*)d_in[0];
    const float* W  = (const float*)d_in[1];
    const float* b  = (const float*)d_in[2];
    const float* A  = (const float*)d_in[3];
    const float* Bm = (const float*)d_in[4];
    const float* sc = (const float*)d_in[5];
    float* out = (float*)d_out;

    const size_t M = 8192, N = 2048, K = 2048;

    unsigned short* Weff = (unsigned short*)d_ws;   // 8 MB

    // 1) Weff = bf16(W + scale * B@A)
    aux_kernel<<<dim3(N * K / 8 / 256), dim3(256), 0, stream>>>(
        W, A, Bm, sc, Weff);

    // 2) out = bf16(x) @ Weff^T + b  (x cvt fused into A-staging)
    gemm_bias_kernel<<<dim3((M / BM) * (N / BN)), dim3(512), 0, stream>>>(
        x, Weff, b, out);
}

// Round 10
// 211.798 us; speedup vs baseline: 1.2186x; 1.2108x over previous
//
#include <hip/hip_runtime.h>
#include <hip/hip_bf16.h>
#include <cstdint>

// Problem: out = x @ (W + scale*B@A)^T + b
//   x[4,2048,2048] -> X[M=8192, K=2048],  W[N=2048, K=2048], b[N],
//   A[R=16, K], B[N, R=16], scale scalar.  ALL I/O IS FLOAT32.
// R11: 32x32 MFMA + f(r)=(r&7)^((r>>3)&3) swizzle -> GEMM 72.6us, total
//      209.5 (best known). MfmaUtil 40%, conflicts 0.
// R8-R14: x-cvt fusion axis -> all worse (spill at 128 VGPR regardless of
//      launch_bounds). AXIS CLOSED; base reverted to R11.
// R15: 4-phase iteration (was 8): merge each tile's two n-half phases.
//      Per phase: 16 MFMA (4 indep acc chains) instead of 8; barriers
//      16 -> 8 per 2-tile iteration. Register set IDENTICAL to R11
//      (bqa+bqb were already both live). Cycle model: per-phase overhead
//      ~850cy was 62% of iteration time at 8 phases; halving phase count
//      amortizes it 2x. Stage plan: 2 regions (4 gloads) per phase,
//      vmcnt(4) at Q2/Q4 ends (never drain); per-slot liveness audited.

typedef __bf16 bf16x8 __attribute__((ext_vector_type(8)));
typedef float floatx16 __attribute__((ext_vector_type(16)));
typedef unsigned short ushort8 __attribute__((ext_vector_type(8)));

#define BM 256
#define BN 256
#define BK 64
#define NT 32   // K / BK

__device__ __forceinline__ void gload_lds16(const void* g, void* l) {
    // 16B-per-lane async global->LDS. LDS dest must be wave-uniform base + lane*16.
    __builtin_amdgcn_global_load_lds((__attribute__((address_space(1))) void*)g,
                                     (__attribute__((address_space(3))) void*)l,
                                     16, 0, 0);
}

// fp32 -> bf16 bits, round-to-nearest-even (finite inputs only).
__device__ __forceinline__ unsigned short f2bf_bits(float f) {
    unsigned int u = __float_as_uint(f);
    u += 0x7FFFu + ((u >> 16) & 1u);
    return (unsigned short)(u >> 16);
}

// ---------------------------------------------------------------------------
// Fused aux kernel (R11 version).
//   blocks [0, 8192):      Xbf = bf16(x)
//   blocks [8192, 10240):  Weff = bf16(W + scale*B@A)
// ---------------------------------------------------------------------------
__global__ __launch_bounds__(256)
void aux_kernel(const float* __restrict__ x, unsigned short* __restrict__ Xbf,
                const float* __restrict__ W, const float* __restrict__ A,
                const float* __restrict__ Bm, const float* __restrict__ scale_p,
                unsigned short* __restrict__ Weff)
{
    const int K = 2048, R = 16;
    int bid = blockIdx.x;
    if (bid < 8192) {
        size_t i = ((size_t)bid * 256 + threadIdx.x) * 8;
        float4 a = *reinterpret_cast<const float4*>(x + i);
        float4 b = *reinterpret_cast<const float4*>(x + i + 4);
        ushort8 o;
        o[0] = f2bf_bits(a.x); o[1] = f2bf_bits(a.y);
        o[2] = f2bf_bits(a.z); o[3] = f2bf_bits(a.w);
        o[4] = f2bf_bits(b.x); o[5] = f2bf_bits(b.y);
        o[6] = f2bf_bits(b.z); o[7] = f2bf_bits(b.w);
        *reinterpret_cast<ushort8*>(Xbf + i) = o;
    } else {
        int t  = (bid - 8192) * 256 + threadIdx.x;
        int n  = t >> 8;
        int k8 = (t & 255) << 3;

        float s = *scale_p;
        float br[16];
#pragma unroll
        for (int r = 0; r < R; ++r)
            br[r] = s * Bm[n * R + r];

        float acc[8] = {0,0,0,0,0,0,0,0};
#pragma unroll
        for (int r = 0; r < R; ++r) {
            const float* ap = A + r * K + k8;
#pragma unroll
            for (int j = 0; j < 8; ++j)
                acc[j] += br[r] * ap[j];
        }

        const float* wp = W + (size_t)n * K + k8;
        ushort8 o;
#pragma unroll
        for (int j = 0; j < 8; ++j)
            o[j] = f2bf_bits(wp[j] + acc[j]);
        *reinterpret_cast<ushort8*>(Weff + (size_t)n * K + k8) = o;
    }
}

// ---------------------------------------------------------------------------
// GEMM: out[M,N] (fp32) = Xbf[M,K] @ Weffbf[N,K]^T + bias (fp32)
//
// LDS regions (16 KB each, 128 KiB total), staged by global_load_lds
// (linear dest, pre-swizzled source):
//   Sa[buf][mh]: A M-half [wrH(2)][64 r][64 c bf16], rows bm+wrH*128+mh*64+r.
//   Sb[buf][nh]: B N-half [wcH(4)][32 r][64 c],      rows bn+wcH*64+nh*32+r.
// Swizzle involution (both sides): 16B slot s -> s ^ (r&7) ^ ((r>>3)&3).
// Measured 0 bank conflicts (R11).
//
// 4 phases / 2 K-tiles (tile t = buf0, t+1 = buf1):
//   Q1 (t,  m0): read Sa00->af, Sb00->bqa, Sb01->bqb (16 b128);
//                stage Sa11,Sb11 <- t1;   BAR lgkm0 16xMFMA BAR
//   Q2 (t,  m1): read Sa01->af (8);
//                stage Sa00,Sb00 <- t2;   BAR lgkm0 16xMFMA VM4 BAR
//   Q3 (t+1,m0): read Sa10->af, Sb10->bqa, Sb11->bqb (16);
//                stage Sa01,Sb01 <- t2;   BAR lgkm0 16xMFMA BAR
//   Q4 (t+1,m1): read Sa11->af (8);
//                stage Sa10,Sb10 <- t3;   BAR lgkm0 16xMFMA VM4 BAR
// vmcnt(4) audit (4 gloads/phase): after prologue-VM4 outstanding =
// {Sa10,Sb10}(4); Q2's VM4 retires {Sa10,Sb10,Sa11,Sb11} before Q3/Q4
// read them; Q4's VM4 retires {Sa00,Sb00,Sa01,Sb01 <- t2} before Q1'/Q2'.
// Write-after-read: every staged region's last read is >=1 closing
// barrier earlier (reads drained by lgkm0 before that barrier).
// ---------------------------------------------------------------------------
#define BAR()       __builtin_amdgcn_s_barrier()
#define WAIT_LGKM() asm volatile("s_waitcnt lgkmcnt(0)" ::: "memory")
#define WAIT_VM4()  asm volatile("s_waitcnt vmcnt(4)" ::: "memory")
#define WAIT_VM0()  asm volatile("s_waitcnt vmcnt(0)" ::: "memory")

#define STAGE_A(buf, mh, kt) do {                                             \
    gload_lds16(gA0 + (size_t)(mh) * 64 * 2048 + (kt) * 64, &Sa[buf][mh][c0 * 8]); \
    gload_lds16(gA1 + (size_t)(mh) * 64 * 2048 + (kt) * 64, &Sa[buf][mh][c1 * 8]); \
} while (0)

#define STAGE_B(buf, nh, kt) do {                                             \
    gload_lds16(gB0 + (size_t)(nh) * 32 * 2048 + (kt) * 64, &Sb[buf][nh][c0 * 8]); \
    gload_lds16(gB1 + (size_t)(nh) * 32 * 2048 + (kt) * 64, &Sb[buf][nh][c1 * 8]); \
} while (0)

// af[mb][ks] <- A quadrant (mh). 8 x ds_read_b128.
#define READ_A(buf, mh) do {                                                  \
    const unsigned short* ra = &Sa[buf][mh][(wr * 64 + l31) * 64];            \
    _Pragma("unroll")                                                         \
    for (int ks = 0; ks < 4; ++ks) {                                          \
        af[0][ks] = *reinterpret_cast<const bf16x8*>(ra + swzk[ks]);          \
        af[1][ks] = *reinterpret_cast<const bf16x8*>(ra + 2048 + swzk[ks]);   \
    }                                                                         \
} while (0)

// BQ[ks] <- B n-block (nh). 4 x ds_read_b128.
#define READ_B(buf, nh, BQ) do {                                              \
    const unsigned short* rb = &Sb[buf][nh][(wc * 32 + l31) * 64];            \
    _Pragma("unroll")                                                         \
    for (int ks = 0; ks < 4; ++ks)                                            \
        BQ[ks] = *reinterpret_cast<const bf16x8*>(rb + swzk[ks]);             \
} while (0)

// 16 x mfma_f32_32x32x16_bf16 for m-half mh x both n-blocks.
// 4 independent acc chains; each chain's consecutive uses 4 slots apart.
#define MFMAPH(mh) do {                                                       \
    __builtin_amdgcn_s_setprio(1);                                            \
    _Pragma("unroll")                                                         \
    for (int ks = 0; ks < 4; ++ks) {                                          \
        acc[(mh)*2+0][0] = __builtin_amdgcn_mfma_f32_32x32x16_bf16(           \
            af[0][ks], bqa[ks], acc[(mh)*2+0][0], 0, 0, 0);                   \
        acc[(mh)*2+1][0] = __builtin_amdgcn_mfma_f32_32x32x16_bf16(           \
            af[1][ks], bqa[ks], acc[(mh)*2+1][0], 0, 0, 0);                   \
        acc[(mh)*2+0][1] = __builtin_amdgcn_mfma_f32_32x32x16_bf16(           \
            af[0][ks], bqb[ks], acc[(mh)*2+0][1], 0, 0, 0);                   \
        acc[(mh)*2+1][1] = __builtin_amdgcn_mfma_f32_32x32x16_bf16(           \
            af[1][ks], bqb[ks], acc[(mh)*2+1][1], 0, 0, 0);                   \
    }                                                                         \
    __builtin_amdgcn_s_setprio(0);                                            \
} while (0)

__global__ __launch_bounds__(512)
void gemm_bias_kernel(const unsigned short* __restrict__ X,
                      const unsigned short* __restrict__ Wt,
                      const float* __restrict__ bias,
                      float* __restrict__ out)
{
    const int N = 2048, K = 2048;

    __shared__ alignas(16) unsigned short Sa[2][2][8192];   // 64 KB
    __shared__ alignas(16) unsigned short Sb[2][2][8192];   // 64 KB

    const int tid  = threadIdx.x;
    const int wave = tid >> 6;
    const int lane = tid & 63;
    const int l31  = lane & 31;
    const int kg   = lane >> 5;   // k-window selector for 32x32 fragments
    const int l7   = lane & 7;
    const int wr   = wave >> 2;   // 0..1  (M split)
    const int wc   = wave & 3;    // 0..3  (N split)

    // XCD-rectangle swizzle (bijective, 256 % 8 == 0).
    const int id  = blockIdx.x;            // 0..255
    const int xcd = id & 7;
    const int sg  = id >> 3;               // 0..31
    const int bm  = (xcd * 4 + (sg & 3)) * BM;
    const int bn  = (sg >> 2) * BN;

    // --- A staging (global_load_lds). Granule c: wrH=c>>9, row=(c>>3)&63,
    // slot=c&7; LDS dest linear; global col pre-swizzled with
    // f(r) = (r&7) ^ ((r>>3)&3).
    const int c0 = tid, c1 = tid + 512;
    const int ar0 = (c0 >> 3) & 63, as0 = c0 & 7;
    const int ar1 = (c1 >> 3) & 63, as1 = c1 & 7;
    const unsigned short* gA0 = X + (size_t)(bm + (c0 >> 9) * 128 + ar0) * K
                                  + ((as0 ^ (ar0 & 7) ^ ((ar0 >> 3) & 3)) << 3);
    const unsigned short* gA1 = X + (size_t)(bm + (c1 >> 9) * 128 + ar1) * K
                                  + ((as1 ^ (ar1 & 7) ^ ((ar1 >> 3) & 3)) << 3);
    // --- B staging. Granule c: wcH=c>>8, row=(c>>3)&31, slot=c&7.
    const int br0 = (c0 >> 3) & 31, br1 = (c1 >> 3) & 31;
    const unsigned short* gB0 = Wt + (size_t)(bn + (c0 >> 8) * 64 + br0) * K
                                   + ((as0 ^ (br0 & 7) ^ ((br0 >> 3) & 3)) << 3);
    const unsigned short* gB1 = Wt + (size_t)(bn + (c1 >> 8) * 64 + br1) * K
                                   + ((as1 ^ (br1 & 7) ^ ((br1 >> 3) & 3)) << 3);

    // ds_read swizzle: logical 16B granule g = ks*2 + kg, phys = g ^ f(row);
    // f(row) = l7 ^ (l31>>3) for every fragment row (offsets ==0 mod 32).
    const int fr   = l7 ^ (l31 >> 3);
    const int swzk[4] = { ((0 + kg) ^ fr) << 3, ((2 + kg) ^ fr) << 3,
                          ((4 + kg) ^ fr) << 3, ((6 + kg) ^ fr) << 3 };

    floatx16 acc[4][2] = {};   // [m-block 0..3][n-block 0..1]
    bf16x8 af[2][4];           // [mb within quadrant][ks]
    bf16x8 bqa[4], bqb[4];     // n-block 0 / n-block 1 of current tile

    // Prologue: 12 gloads. First 8 = regions Q1/Q2 read (Sa00,Sb00,Sb01,
    // Sa01 <- t0); last 4 = {Sa10,Sb10 <- t1}. vmcnt(4) retires first 8,
    // leaves 4 in flight == steady-state entry. Q1(0) stages Sa11,Sb11<-t1.
    STAGE_A(0, 0, 0);
    STAGE_B(0, 0, 0);
    STAGE_B(0, 1, 0);
    STAGE_A(0, 1, 0);
    STAGE_A(1, 0, 1);
    STAGE_B(1, 0, 1);
    WAIT_VM4(); BAR();

#pragma unroll 1
    for (int tt = 0; tt < NT; tt += 2) {
        const int t1 = tt + 1;
        const int t2 = (tt + 2 < NT) ? tt + 2 : NT - 1;   // clamped tail
        const int t3 = (tt + 3 < NT) ? tt + 3 : NT - 1;   // (dead regions)

        // Q1 (tile t, m0)
        READ_A(0, 0); READ_B(0, 0, bqa); READ_B(0, 1, bqb);
        STAGE_A(1, 1, t1); STAGE_B(1, 1, t1);
        BAR(); WAIT_LGKM(); MFMAPH(0); BAR();
        // Q2 (tile t, m1)
        READ_A(0, 1);
        STAGE_A(0, 0, t2); STAGE_B(0, 0, t2);
        BAR(); WAIT_LGKM(); MFMAPH(1); WAIT_VM4(); BAR();
        // Q3 (tile t+1, m0)
        READ_A(1, 0); READ_B(1, 0, bqa); READ_B(1, 1, bqb);
        STAGE_A(0, 1, t2); STAGE_B(0, 1, t2);
        BAR(); WAIT_LGKM(); MFMAPH(0); BAR();
        // Q4 (tile t+1, m1)
        READ_A(1, 1);
        STAGE_A(1, 0, t3); STAGE_B(1, 0, t3);
        BAR(); WAIT_LGKM(); MFMAPH(1); WAIT_VM4(); BAR();
    }
    WAIT_VM0();   // drain tail stages before epilogue stores

    // Epilogue. 32x32 C/D layout (m74/m101): col = lane&31,
    // row = (reg&3) + 8*(reg>>2) + 4*(lane>>5), reg in [0,16).
    const float bsv0 = bias[bn + wc * 64 + l31];
    const float bsv1 = bias[bn + wc * 64 + 32 + l31];
    const size_t cb  = (size_t)bn + wc * 64 + l31;
#pragma unroll
    for (int mb = 0; mb < 4; ++mb) {
#pragma unroll
        for (int r = 0; r < 16; ++r) {
            size_t rowoff = (size_t)(bm + wr * 128 + mb * 32
                                     + (r & 3) + ((r >> 2) << 3) + (kg << 2)) * N;
            out[rowoff + cb]      = acc[mb][0][r] + bsv0;
            out[rowoff + cb + 32] = acc[mb][1][r] + bsv1;
        }
    }
}

extern "C" void kernel_launch(void* const* d_in, const int* in_sizes, int n_in,
                              void* d_out, int out_size, void* d_ws, size_t ws_size,
                              hipStream_t stream)
{
    const float* x  = (const float*)d_in[0];
    const float* W  = (const float*)d_in[1];
    const float* b  = (const float*)d_in[2];
    const float* A  = (const float*)d_in[3];
    const float* Bm = (const float*)d_in[4];
    const float* sc = (const float*)d_in[5];
    float* out = (float*)d_out;

    const size_t M = 8192, N = 2048, K = 2048;

    unsigned short* Xbf  = (unsigned short*)d_ws;                 // 32 MB
    unsigned short* Weff = (unsigned short*)d_ws + M * K;         // + 8 MB

    // 1) fused: Xbf = bf16(x); Weff = bf16(W + scale * B@A)
    aux_kernel<<<dim3((M * K + N * K) / 8 / 256), dim3(256), 0, stream>>>(
        x, Xbf, W, A, Bm, sc, Weff);

    // 2) out = Xbf @ Weff^T + b  (fp32 out), 256 blocks = 256 CUs, no tails
    gemm_bias_kernel<<<dim3((M / BM) * (N / BN)), dim3(512), 0, stream>>>(
        Xbf, Weff, b, out);
}